// Round 8
// baseline (185.069 us; speedup 1.0000x reference)
//
#include <hip/hip_runtime.h>

// Block-sparse causal flash attention, MI355X gfx950.
// B=2 T=2048 H=16 D=128; BLOCK_M=BLOCK_N=64; mask[B,H,32,32] int32.
// R17 (post-mortem of R16): WAVE-LEVEL SOFTWARE PIPELINE. R16 (barrier-free,
// K/V from L2, 0 bank conflicts) was 65us — WORSE than the 56us barrier
// kernels => barriers were never the wall. Per-iteration wall ~4-6k cycles
// vs ~600 cycles of issued work, all pipes <20%: the wall is SERIALIZED
// LATENCY EXPOSURE (K load -> use at iter start, V mid-iter; ~300+cyc each,
// 2 waves/SIMD can't cover). R15/R16 regressed vs R9/R14 because dropping
// LDS staging also dropped its one-tile-ahead prefetch.
// R17 = R16 + register double-buffer prefetch (no cross-wave coordination
// needed in the barrier-free structure):
//  - K frags double-buffered ACROSS iterations (KA/KB, 8x half8 each):
//    K[t+1] issued before computing tile t => full-body (~500cyc) hiding;
//  - all 8 V frags issued at body TOP, consumed after QK+softmax (~330cyc);
//  - per-iteration exposure ~0; regs ~186 arch + 64 acc <= 256 @ (256,2).
// Kept verbatim from R16 (verified): frag images, per-XCD LPT queues,
// 2-wave-pair items w/ LDS flag handshake epilogue, swapped-operand QK^T,
// in-register P pack (cvt_pkrtz + permlane32_swap), static-max softmax.
// K image: frag[(half*8+kc)*64+lane]*8 holds K[32*half + (lane&31)]
//          [kc*16 + (lane>>5)*8 .. +8]
// V image: frag[(wc*4+dt)*2+kvc]*512 + lane*8 holds V[d=dt*32+(lane&31)]
//          [s = 32*wc + kvc*16 + (lane>>5)*8 .. +8]

typedef _Float16 half8 __attribute__((ext_vector_type(8)));
typedef float floatx16 __attribute__((ext_vector_type(16)));
typedef unsigned int uint4v __attribute__((ext_vector_type(4)));

#define B_ 2
#define T_ 2048
#define H_ 16
#define D_ 128
#define BM 64
#define BN 64
#define NQ (T_ / BM)
#define NK (T_ / BN)
#define NXCD 8
#define PPX 4               // bh-pairs per XCD
#define NL2 (PPX * 64)      // 256 items (32-row) per XCD queue
#define TILE_HALVES 8192    // one 64x128 f16 tile image

__device__ inline half8 cvt8(const float4 a, const float4 b) {
    half8 r;
    r[0] = (_Float16)a.x; r[1] = (_Float16)a.y;
    r[2] = (_Float16)a.z; r[3] = (_Float16)a.w;
    r[4] = (_Float16)b.x; r[5] = (_Float16)b.y;
    r[6] = (_Float16)b.z; r[7] = (_Float16)b.w;
    return r;
}

// ---------------- pre-pass: cast + relayout K/V into frag images ----------
__global__ __launch_bounds__(256)
void cast_kv_kernel(const float* __restrict__ kg, const float* __restrict__ vg,
                    const int* __restrict__ maskg,
                    _Float16* __restrict__ wsk, _Float16* __restrict__ wsv,
                    int* __restrict__ ws_act, int* __restrict__ ws_ctr)
{
    const int tile = blockIdx.x;           // pair*32 + j, 1024 tiles
    const int pair = tile >> 5;
    const int j    = tile & 31;
    const int b    = pair >> 4;
    const int h    = pair & 15;
    const int tid  = threadIdx.x;

    const size_t rowstr = H_ * D_;
    const size_t base = ((size_t)b * T_ + (size_t)j * BN) * rowstr + (size_t)h * D_;
    _Float16* imk = wsk + (size_t)tile * TILE_HALVES;
    _Float16* imv = wsv + (size_t)tile * TILE_HALVES;

    // K: A-frag layout [half][kc][lane]: lane = (s&31) + 32*hi holds
    // K[32*half + (s&31)][kc*16 + hi*8 .. +8]
    #pragma unroll
    for (int kk = 0; kk < 4; ++kk) {
        const int c  = tid + 256 * kk;
        const int s  = c >> 4;
        const int d8 = (c & 15) << 3;
        const float* kp = kg + base + (size_t)s * rowstr + d8;
        float4 a  = *(const float4*)kp;
        float4 bb = *(const float4*)(kp + 4);
        const int half = s >> 5;
        const int kc   = d8 >> 4;
        const int hiv  = (d8 >> 3) & 1;
        const int lanev = (s & 31) + 32 * hiv;
        *(half8*)(&imk[((half * 8 + kc) * 64 + lanev) * 8]) = cvt8(a, bb);
    }
    // V: frag layout [wcv][dt][kvcv][lane]
    const int vd  = (tid & 63) * 2;
    const int vsg = tid >> 6;
    #pragma unroll
    for (int p = 0; p < 2; ++p) {
        half8 r0, r1;
        #pragma unroll
        for (int i = 0; i < 8; ++i) {
            const float* vp = vg + base + (size_t)(vsg * 16 + p * 8 + i) * rowstr + vd;
            float2 vv = *(const float2*)vp;
            r0[i] = (_Float16)vv.x;
            r1[i] = (_Float16)vv.y;
        }
        const int sb   = vsg * 16 + p * 8;
        const int wcv  = sb >> 5;
        const int kvcv = (sb >> 4) & 1;
        const int hiv  = (sb >> 3) & 1;
        const int f0   = ((wcv * 4 + (vd >> 5)) * 2 + kvcv) * 512 + (hiv * 32 + (vd & 31)) * 8;
        const int f1   = ((wcv * 4 + ((vd + 1) >> 5)) * 2 + kvcv) * 512 + (hiv * 32 + ((vd + 1) & 31)) * 8;
        *(half8*)(&imv[f0]) = r0;
        *(half8*)(&imv[f1]) = r1;
    }

    // act masks: mask row j serves items qi32 = 2j and 2j+1.
    // Queue layout [xcd][rank], rank = (63-qi32)*PPX + (pair&3) (LPT).
    if (tid < 64) {
        int pred = 0;
        if (tid < 32 && tid <= j)
            pred = (maskg[(((size_t)b * H_ + h) * NQ + j) * NK + tid] != 0);
        unsigned long long bal = __ballot(pred);
        if (tid == 0) {
            const int a32 = (int)(unsigned)bal;
            const int qb  = pair >> 2;       // xcd
            const int pl  = pair & 3;
            ws_act[qb * NL2 + (63 - (2 * j)) * PPX + pl]     = a32;
            ws_act[qb * NL2 + (63 - (2 * j + 1)) * PPX + pl] = a32;
        }
    }
    if (tile < NXCD && tid == 0) ws_ctr[tile] = 0;
}

// ---------------- main: barrier-free + register-pipelined tile loop ------
__global__ __launch_bounds__(256, 2)
void bsattn_kernel(const float* __restrict__ qg,
                   const _Float16* __restrict__ wsk,
                   const _Float16* __restrict__ wsv,
                   const int* __restrict__ ws_act,
                   int* __restrict__ ws_ctr,
                   float* __restrict__ outg)
{
    const int xcd  = blockIdx.x & 7;
    int* ctr = ws_ctr + xcd;
    const int* act_q = ws_act + xcd * NL2;

    const int tid  = threadIdx.x;
    const int wave = tid >> 6;
    const int pr   = wave >> 1;                // pair within block (0,1)
    const int wc   = wave & 1;                 // kv half
    const int lane = tid & 63;
    const int l31  = lane & 31;
    const int hi   = lane >> 5;

    __shared__ float Ebuf[2][2048];            // 8KB exchange buf per pair
    __shared__ float lbuf[2][2][32];
    __shared__ int fl0[2], fl1[2], slot[2];
    if (tid < 2) { fl0[tid] = 0; fl1[tid] = 0; }
    __syncthreads();                           // one-time init

    const float cs2 = 0.08838834764831845f * 1.44269504088896341f;
    const float C2  = 6.0f * 1.44269504088896341f;
    const int vbase = wc * 4096 + lane * 8;
    const int kbase = wc * 4096 + lane * 8;

    int* myf   = (wc == 0) ? &fl0[pr] : &fl1[pr];
    int* peerf = (wc == 0) ? &fl1[pr] : &fl0[pr];
    int pub = 0;

    auto publish = [&](int v) {
        if (lane == 0)
            __hip_atomic_store(myf, v, __ATOMIC_RELEASE, __HIP_MEMORY_SCOPE_WORKGROUP);
    };
    auto await = [&](int target) {
        while (__hip_atomic_load(peerf, __ATOMIC_ACQUIRE, __HIP_MEMORY_SCOPE_WORKGROUP) < target)
            __builtin_amdgcn_s_sleep(2);
    };

    half8 qf[8];
    int k = 0;

    #pragma unroll 1
    while (true) {
        // ---- grab (wc0 publishes rank via slot; wc1 awaits) ----
        int rank;
        if (wc == 0) {
            int r = 0;
            if (lane == 0) r = atomicAdd(ctr, 1);
            r = __shfl(r, 0);
            slot[pr] = r;
            publish(++pub);                    // f0 = 3k+1
            rank = r;
        } else {
            await(3 * k + 1);
            rank = slot[pr];
        }
        if (rank >= NL2) break;                // uniform per pair

        const int qi32 = 63 - (rank >> 2);
        const int bh   = xcd * PPX + (rank & 3);
        const int b    = bh >> 4;
        const int h    = bh & 15;
        const size_t tilebase = (size_t)bh * NK * TILE_HALVES;
        const int diag = qi32 >> 1;
        unsigned actw = (unsigned)act_q[rank];
        if (wc == 1 && !(qi32 & 1)) actw &= ~(1u << diag);  // fully-masked half

        // Q frags: 32 rows, both waves load identically (q in lanes)
        {
            const int qrow = qi32 * 32 + l31;
            const float* qp = qg + (((size_t)b * T_ + qrow) * H_ + h) * D_;
            #pragma unroll
            for (int kc = 0; kc < 8; ++kc) {
                float4 a = *(const float4*)(qp + kc * 16 + hi * 8);
                float4 c = *(const float4*)(qp + kc * 16 + hi * 8 + 4);
                qf[kc] = cvt8(a, c);
            }
        }

        floatx16 acc[4];
        #pragma unroll
        for (int u = 0; u < 4; ++u) acc[u] = (floatx16)0.0f;
        float lf0 = 0.0f, lf1 = 0.0f, lf2 = 0.0f, lf3 = 0.0f;

        auto loadK = [&](half8* K, int j) {
            const _Float16* imk = wsk + tilebase + (size_t)j * TILE_HALVES + kbase;
            #pragma unroll
            for (int i = 0; i < 8; ++i) K[i] = *(const half8*)(imk + i * 512);
        };

        // body: V issued at TOP (consumed after QK+softmax ~330cyc later);
        // K for THIS tile already resident (prefetched last iteration).
        auto body = [&](const half8* K, int j) {
            const _Float16* imv = wsv + tilebase + (size_t)j * TILE_HALVES + vbase;
            half8 v0 = *(const half8*)(imv + 0 * 1024 + 0 * 512);
            half8 v1 = *(const half8*)(imv + 0 * 1024 + 1 * 512);
            half8 v2 = *(const half8*)(imv + 1 * 1024 + 0 * 512);
            half8 v3 = *(const half8*)(imv + 1 * 1024 + 1 * 512);
            half8 v4 = *(const half8*)(imv + 2 * 1024 + 0 * 512);
            half8 v5 = *(const half8*)(imv + 2 * 1024 + 1 * 512);
            half8 v6 = *(const half8*)(imv + 3 * 1024 + 0 * 512);
            half8 v7 = *(const half8*)(imv + 3 * 1024 + 1 * 512);

            // S^T via swapped operands: two independent 4-chains
            floatx16 s0 = (floatx16)0.0f, s1 = (floatx16)0.0f;
            s0 = __builtin_amdgcn_mfma_f32_32x32x16_f16(K[0], qf[0], s0, 0, 0, 0);
            s1 = __builtin_amdgcn_mfma_f32_32x32x16_f16(K[4], qf[4], s1, 0, 0, 0);
            s0 = __builtin_amdgcn_mfma_f32_32x32x16_f16(K[1], qf[1], s0, 0, 0, 0);
            s1 = __builtin_amdgcn_mfma_f32_32x32x16_f16(K[5], qf[5], s1, 0, 0, 0);
            s0 = __builtin_amdgcn_mfma_f32_32x32x16_f16(K[2], qf[2], s0, 0, 0, 0);
            s1 = __builtin_amdgcn_mfma_f32_32x32x16_f16(K[6], qf[6], s1, 0, 0, 0);
            s0 = __builtin_amdgcn_mfma_f32_32x32x16_f16(K[3], qf[3], s0, 0, 0, 0);
            s1 = __builtin_amdgcn_mfma_f32_32x32x16_f16(K[7], qf[7], s1, 0, 0, 0);

            // softmax + in-register P^T pack
            const bool dm = (j == diag) && (wc == (qi32 & 1));
            unsigned int u0, u1, u2, u3, u4, u5, u6, u7;
            {
                float pv[16];
                #pragma unroll
                for (int r = 0; r < 16; ++r) {
                    float sv = s0[r] + s1[r];
                    const int rkv = (r & 3) + 8 * (r >> 2) + 4 * hi;
                    if (dm && (rkv > l31)) sv = -INFINITY;
                    pv[r] = __builtin_amdgcn_exp2f(__builtin_fmaf(sv, cs2, -C2));
                }
                #pragma unroll
                for (int r = 0; r < 4; ++r)   lf0 += pv[r];
                #pragma unroll
                for (int r = 4; r < 8; ++r)   lf1 += pv[r];
                #pragma unroll
                for (int r = 8; r < 12; ++r)  lf2 += pv[r];
                #pragma unroll
                for (int r = 12; r < 16; ++r) lf3 += pv[r];
                u0 = __builtin_bit_cast(unsigned int, __builtin_amdgcn_cvt_pkrtz(pv[0],  pv[1]));
                u1 = __builtin_bit_cast(unsigned int, __builtin_amdgcn_cvt_pkrtz(pv[2],  pv[3]));
                u2 = __builtin_bit_cast(unsigned int, __builtin_amdgcn_cvt_pkrtz(pv[4],  pv[5]));
                u3 = __builtin_bit_cast(unsigned int, __builtin_amdgcn_cvt_pkrtz(pv[6],  pv[7]));
                u4 = __builtin_bit_cast(unsigned int, __builtin_amdgcn_cvt_pkrtz(pv[8],  pv[9]));
                u5 = __builtin_bit_cast(unsigned int, __builtin_amdgcn_cvt_pkrtz(pv[10], pv[11]));
                u6 = __builtin_bit_cast(unsigned int, __builtin_amdgcn_cvt_pkrtz(pv[12], pv[13]));
                u7 = __builtin_bit_cast(unsigned int, __builtin_amdgcn_cvt_pkrtz(pv[14], pv[15]));
            }
            asm("v_permlane32_swap_b32 %0, %1" : "+v"(u0), "+v"(u2));
            asm("v_permlane32_swap_b32 %0, %1" : "+v"(u1), "+v"(u3));
            asm("v_permlane32_swap_b32 %0, %1" : "+v"(u4), "+v"(u6));
            asm("v_permlane32_swap_b32 %0, %1" : "+v"(u5), "+v"(u7));
            const half8 pf0 = __builtin_bit_cast(half8, (uint4v){u0, u1, u2, u3});
            const half8 pf1 = __builtin_bit_cast(half8, (uint4v){u4, u5, u6, u7});

            acc[0] = __builtin_amdgcn_mfma_f32_32x32x16_f16(v0, pf0, acc[0], 0, 0, 0);
            acc[0] = __builtin_amdgcn_mfma_f32_32x32x16_f16(v1, pf1, acc[0], 0, 0, 0);
            acc[1] = __builtin_amdgcn_mfma_f32_32x32x16_f16(v2, pf0, acc[1], 0, 0, 0);
            acc[1] = __builtin_amdgcn_mfma_f32_32x32x16_f16(v3, pf1, acc[1], 0, 0, 0);
            acc[2] = __builtin_amdgcn_mfma_f32_32x32x16_f16(v4, pf0, acc[2], 0, 0, 0);
            acc[2] = __builtin_amdgcn_mfma_f32_32x32x16_f16(v5, pf1, acc[2], 0, 0, 0);
            acc[3] = __builtin_amdgcn_mfma_f32_32x32x16_f16(v6, pf0, acc[3], 0, 0, 0);
            acc[3] = __builtin_amdgcn_mfma_f32_32x32x16_f16(v7, pf1, acc[3], 0, 0, 0);
        };

        // ---- tile loop: K register double-buffer, unroll-2, no sync ----
        unsigned rem = actw;
        half8 KA[8], KB[8];
        if (rem) {
            int jA = __ffs(rem) - 1; rem &= rem - 1;
            loadK(KA, jA);
            #pragma unroll 1
            while (true) {
                int jn = -1;
                if (rem) { jn = __ffs(rem) - 1; rem &= rem - 1; loadK(KB, jn); }
                body(KA, jA);                  // KB loads in flight
                if (jn < 0) break;
                int jn2 = -1;
                if (rem) { jn2 = __ffs(rem) - 1; rem &= rem - 1; loadK(KA, jn2); }
                body(KB, jn);                  // KA loads in flight
                if (jn2 < 0) break;
                jA = jn2;
            }
        }

        // ---- pair epilogue: exchange O halves + l via LDS handshake ----
        const float lacc_f = (lf0 + lf1) + (lf2 + lf3);
        const float lmine = lacc_f + __shfl_xor(lacc_f, 32);
        float* Eb = &Ebuf[pr][0];
        const int qrow = qi32 * 32 + l31;
        float* op = outg + (((size_t)b * T_ + qrow) * H_ + h) * D_;

        if (wc == 0) {
            await(2 * k);                      // partner done with prev bufs
            if (hi == 0) lbuf[pr][0][l31] = lmine;
            publish(++pub);                    // f0 = 3k+2 (lbuf visible)
            await(2 * k + 1);                  // A + lbuf[1] ready
            const float inv = 1.0f / (lmine + lbuf[pr][1][l31]);
            #pragma unroll
            for (int dt = 0; dt < 2; ++dt) {
                #pragma unroll
                for (int g = 0; g < 4; ++g) {
                    const int idx = ((dt * 4 + g) * 2 + hi) * 32 + l31;
                    float4 p = *(const float4*)(&Eb[idx * 4]);
                    float4 o;
                    o.x = (acc[dt][4 * g + 0] + p.x) * inv;
                    o.y = (acc[dt][4 * g + 1] + p.y) * inv;
                    o.z = (acc[dt][4 * g + 2] + p.z) * inv;
                    o.w = (acc[dt][4 * g + 3] + p.w) * inv;
                    *(float4*)(op + dt * 32 + g * 8 + hi * 4) = o;
                }
            }
            #pragma unroll
            for (int dt = 2; dt < 4; ++dt) {   // write B
                #pragma unroll
                for (int g = 0; g < 4; ++g) {
                    float4 val;
                    val.x = acc[dt][4 * g + 0];
                    val.y = acc[dt][4 * g + 1];
                    val.z = acc[dt][4 * g + 2];
                    val.w = acc[dt][4 * g + 3];
                    const int idx = (((dt - 2) * 4 + g) * 2 + hi) * 32 + l31;
                    *(float4*)(&Eb[idx * 4]) = val;
                }
            }
            publish(++pub);                    // f0 = 3k+3 (B visible)
        } else {
            if (hi == 0) lbuf[pr][1][l31] = lmine;
            #pragma unroll
            for (int dt = 0; dt < 2; ++dt) {   // write A
                #pragma unroll
                for (int g = 0; g < 4; ++g) {
                    float4 val;
                    val.x = acc[dt][4 * g + 0];
                    val.y = acc[dt][4 * g + 1];
                    val.z = acc[dt][4 * g + 2];
                    val.w = acc[dt][4 * g + 3];
                    const int idx = ((dt * 4 + g) * 2 + hi) * 32 + l31;
                    *(float4*)(&Eb[idx * 4]) = val;
                }
            }
            publish(++pub);                    // f1 = 2k+1 (A + lbuf visible)
            await(3 * k + 3);                  // lbuf[0] + B ready
            const float inv = 1.0f / (lmine + lbuf[pr][0][l31]);
            #pragma unroll
            for (int dt = 2; dt < 4; ++dt) {
                #pragma unroll
                for (int g = 0; g < 4; ++g) {
                    const int idx = (((dt - 2) * 4 + g) * 2 + hi) * 32 + l31;
                    float4 p = *(const float4*)(&Eb[idx * 4]);
                    float4 o;
                    o.x = (acc[dt][4 * g + 0] + p.x) * inv;
                    o.y = (acc[dt][4 * g + 1] + p.y) * inv;
                    o.z = (acc[dt][4 * g + 2] + p.z) * inv;
                    o.w = (acc[dt][4 * g + 3] + p.w) * inv;
                    *(float4*)(op + dt * 32 + g * 8 + hi * 4) = o;
                }
            }
            publish(++pub);                    // f1 = 2k+2 (done reading)
        }
        ++k;
    }
}

extern "C" void kernel_launch(void* const* d_in, const int* in_sizes, int n_in,
                              void* d_out, int out_size, void* d_ws, size_t ws_size,
                              hipStream_t stream) {
    const float* q  = (const float*)d_in[0];
    const float* k  = (const float*)d_in[1];
    const float* v  = (const float*)d_in[2];
    const int* mask = (const int*)d_in[3];
    float* out      = (float*)d_out;

    _Float16* wsk = (_Float16*)d_ws;                              // 16.8 MB
    _Float16* wsv = wsk + (size_t)B_ * H_ * NK * TILE_HALVES;     // +16.8 MB
    int* ws_act   = (int*)(wsv + (size_t)B_ * H_ * NK * TILE_HALVES);  // +8 KB
    int* ws_ctr   = ws_act + NXCD * NL2;                          // +32 B

    cast_kv_kernel<<<dim3(B_ * H_ * NK), 256, 0, stream>>>(k, v, mask, wsk, wsv,
                                                           ws_act, ws_ctr);
    bsattn_kernel<<<dim3(512), 256, 0, stream>>>(q, wsk, wsv, ws_act, ws_ctr, out);
}